// Round 11
// baseline (136.470 us; speedup 1.0000x reference)
//
#include <hip/hip_runtime.h>
#include <math.h>

// Problem constants
constexpr int Bn = 32;
constexpr int Cn = 512;
constexpr int Tn = 1024;
constexpr int KS = 13;

// Tiling: ONE wave per block; each block owns (b, 8-channel group).
constexpr int CBW = 8;             // channels per wave
constexpr int HRW = CBW + KS - 1;  // 20 halo rows per wave
constexpr int TT  = 64;            // timesteps per chunk
constexpr int NCH = Tn / TT;       // 16 chunks
constexpr int DST = TT + 1;        // LDS drive stride (conflict-free)

// 2048 blocks (32 b x 64 c-groups) x 64 threads = 8 independent waves/CU.
// r6-r10 post-mortem: four different memory pipelines all pinned at 47.5us
// -> the wall was the cross-wave producer/consumer handshake chain (~7100
// cyc/chunk vs ~2600 modeled), not the memory system. This kernel has ZERO
// cross-wave communication: conv (lane=t, in-register sliding window) and
// scan (lane=channel) live in the SAME wave, glued by an intra-wave LDS
// transpose ordered by lgkmcnt only. No atomics, no spins, no barriers.
// 8 waves/CU hide each other's vmcnt / dep-chain stalls.
// All fp32 math uses explicit _rn intrinsics (one rounding per numpy op, no
// FMA) — bit-identical to the validated round-2..10 kernels.

#define SCAN16(DV, TB)                                                   \
  _Pragma("unroll")                                                      \
  for (int j = 0; j < 16; ++j) {                                         \
    const float rthr = (mem > 0.5f) ? 0.5f : 0.0f;  /* reset: OLD mem */ \
    float a_  = __fmul_rn(0.95f, mem);                                   \
    float s2_ = __fadd_rn(a_, DV[j]);                                    \
    mem = __fsub_rn(s2_, rthr);                                          \
    const unsigned int bit = (mem > 0.5f) ? 1u : 0u;                     \
    if ((TB) + j < 32) lo |= bit << ((TB) + j);                          \
    else               hi |= bit << ((TB) + j - 32);                     \
  }

__global__ __launch_bounds__(64, 2)
void snn_fused(const float* __restrict__ x, const float* __restrict__ wp,
               float* __restrict__ out) {
  __shared__ float Dv[CBW][DST];            // drive tile, 2.1 KB (per wave)
  __shared__ unsigned long long Mk[CBW];    // spike bitmasks, 64 B

  const int lane = threadIdx.x;             // = t within chunk (conv/store)
  const int b    = blockIdx.y;
  const int c0   = blockIdx.x * CBW;
  const long obase = ((long)b * Cn + c0) * Tn;

  // ---- Gaussian weights, numpy float32 bit-emulation (validated) ----
  float kw[KS];
  {
    float w  = wp[0];
    float wc = fminf(fmaxf(w, 1.0f), 10.0f);      // clip(w, 1, 10)
    float sigma = __fadd_rn(5.5f, wc);
    float e[KS];
#pragma unroll
    for (int i = 0; i < KS; ++i) {
      float q = __fdiv_rn((float)(i - 6), sigma);
      float t = __fmul_rn(-0.5f, __fmul_rn(q, q));
      e[i] = (float)exp((double)t);
    }
    // numpy pairwise_sum order for n=13
    float s = __fadd_rn(
        __fadd_rn(__fadd_rn(e[0], e[1]), __fadd_rn(e[2], e[3])),
        __fadd_rn(__fadd_rn(e[4], e[5]), __fadd_rn(e[6], e[7])));
    s = __fadd_rn(s, e[8]);  s = __fadd_rn(s, e[9]);  s = __fadd_rn(s, e[10]);
    s = __fadd_rn(s, e[11]); s = __fadd_rn(s, e[12]);
#pragma unroll
    for (int i = 0; i < KS; ++i) kw[i] = __fdiv_rn(e[i], s);
  }

  // OOB mask over the 20 halo rows (wave-uniform)
  unsigned oobm = 0u;
#pragma unroll
  for (int j = 0; j < HRW; ++j) {
    const int gc = c0 - 6 + j;
    if (gc < 0 || gc >= Cn) oobm |= 1u << j;
  }
  // Uniform row base pointers (clamped; garbage rows masked at use)
  const float* rb[HRW];
#pragma unroll
  for (int j = 0; j < HRW; ++j) {
    int gc = c0 - 6 + j;
    gc = gc < 0 ? 0 : (gc > Cn - 1 ? Cn - 1 : gc);
    rb[j] = x + ((long)b * Cn + gc) * Tn;
  }

  auto loadc = [&](int m, float* dst) {     // 20 coalesced 256B row-loads
#pragma unroll
    for (int j = 0; j < HRW; ++j) dst[j] = rb[j][m * TT + lane];
  };
  auto convc = [&](const float* xr) {       // mask at USE (vmcnt wait here)
    float xs[HRW];
#pragma unroll
    for (int j = 0; j < HRW; ++j)
      xs[j] = ((oobm >> j) & 1u) ? 0.0f : xr[j];      // zero pad in regs
#pragma unroll
    for (int r = 0; r < CBW; ++r) {
      float acc = __fmul_rn(kw[0], xs[r]);            // ascending, no FMA
#pragma unroll
      for (int i = 1; i < KS; ++i)
        acc = __fadd_rn(acc, __fmul_rn(kw[i], xs[r + i]));
      Dv[r][lane] = __fsub_rn(xs[r + 6], acc);        // x - x_mean
    }
  };

  float xA[HRW], xB[HRW];                   // ping-pong (r7-proven pattern)
  float mem = 0.0f;                         // scan state (lanes 0..7)

  // STEP: issue loads k+1 first (deep queue), conv k, intra-wave transpose,
  // 8-lane scan chain, mask broadcast, 8 coalesced fire-and-forget stores.
#define STEP(K, XP, XN)                                                  \
  do {                                                                   \
    if ((K) + 1 < NCH) loadc((K) + 1, XN);                               \
    convc(XP);                                                           \
    __asm__ __volatile__("s_waitcnt lgkmcnt(0)" ::: "memory");           \
    if (lane < CBW) {                                                    \
      const float* Dc = &Dv[lane][0];                                    \
      unsigned int lo = 0u, hi = 0u;                                     \
      float dvA[16], dvB[16];               /* named, const idx only */  \
      _Pragma("unroll") for (int j = 0; j < 16; ++j) dvA[j] = Dc[j];     \
      _Pragma("unroll") for (int j = 0; j < 16; ++j) dvB[j] = Dc[16 + j];\
      SCAN16(dvA, 0)                                                     \
      _Pragma("unroll") for (int j = 0; j < 16; ++j) dvA[j] = Dc[32 + j];\
      SCAN16(dvB, 16)                                                    \
      _Pragma("unroll") for (int j = 0; j < 16; ++j) dvB[j] = Dc[48 + j];\
      SCAN16(dvA, 32)                                                    \
      SCAN16(dvB, 48)                                                    \
      Mk[lane] = ((unsigned long long)hi << 32) | (unsigned long long)lo;\
    }                                                                    \
    __asm__ __volatile__("s_waitcnt lgkmcnt(0)" ::: "memory");           \
    {                                                                    \
      const int t0p = (K) * TT;                                          \
      _Pragma("unroll")                                                  \
      for (int r = 0; r < CBW; ++r) {                                    \
        const unsigned long long wb = Mk[r];       /* LDS broadcast */   \
        out[obase + (long)r * Tn + t0p + lane] =                         \
            ((wb >> lane) & 1ull) ? 1.0f : 0.0f;   /* fire & forget */   \
      }                                                                  \
    }                                                                    \
  } while (0)

  loadc(0, xA);
  for (int kb = 0; kb < NCH; kb += 2) {     // NCH even: clean ping-pong
    STEP(kb + 0, xA, xB);
    STEP(kb + 1, xB, xA);
  }
#undef STEP
}

extern "C" void kernel_launch(void* const* d_in, const int* in_sizes, int n_in,
                              void* d_out, int out_size, void* d_ws, size_t ws_size,
                              hipStream_t stream) {
  const float* x  = (const float*)d_in[0];
  const float* w  = (const float*)d_in[1];
  float* out      = (float*)d_out;
  dim3 grid(Cn / CBW, Bn, 1);               // 64 x 32 = 2048 one-wave blocks
  snn_fused<<<grid, 64, 0, stream>>>(x, w, out);
}